// Round 1
// baseline (343.210 us; speedup 1.0000x reference)
//
#include <hip/hip_runtime.h>
#include <hip/hip_bf16.h>

#define V_ 32000
#define E_ 100
#define H_ 128
#define B_ 1024
#define T_ 256

typedef float f32x4 __attribute__((ext_vector_type(4)));
typedef __bf16 bf16x8 __attribute__((ext_vector_type(8)));

__device__ __forceinline__ f32x4 mfma16(bf16x8 a, bf16x8 b, f32x4 c) {
    return __builtin_amdgcn_mfma_f32_16x16x32_bf16(a, b, c, 0, 0, 0);
}

__device__ __forceinline__ void split_bf16(float v, __bf16& hi, __bf16& lo) {
    hi = (__bf16)v;
    lo = (__bf16)(v - (float)hi);
}

__device__ __forceinline__ void cvt8(f32x4 p0, f32x4 p1, bf16x8& hi, bf16x8& lo) {
#pragma unroll
    for (int e = 0; e < 4; ++e) {
        __bf16 h1, l1; split_bf16(p0[e], h1, l1);
        hi[e] = h1; lo[e] = l1;
        __bf16 h2, l2; split_bf16(p1[e], h2, l2);
        hi[4 + e] = h2; lo[4 + e] = l2;
    }
}

// ---------------------------------------------------------------------------
// K1: xp[tq][b][h] = emb[x[b,t]] @ W_ih^T + b_ih + b_hh   (K=100 padded to 128)
// grid: (B/128, len) ; block 512 (8 waves). Tile 128(batch) x 128(H).
// ---------------------------------------------------------------------------
__global__ __launch_bounds__(512, 1) void k1_xproj(
    const int* __restrict__ x, const float* __restrict__ emb,
    const float* __restrict__ Wih, const float* __restrict__ bih,
    const float* __restrict__ bhh, float* __restrict__ xp, int t0)
{
    __shared__ __bf16 Ah[16384], Al[16384], Bh[16384], Bl[16384];
    __shared__ int xidx[128];
    const int tid = threadIdx.x;
    const int b0 = blockIdx.x * 128;
    const int tq = blockIdx.y;
    const int t = t0 + tq;

    if (tid < 128) xidx[tid] = x[(size_t)(b0 + tid) * T_ + t];

    // stage B granules: B[k][h] = W_ih[h][k], rows = h, row length 100
    for (int g = tid; g < 2048; g += 512) {
        int row = g >> 4, gk = g & 15;
        int k0 = gk * 8;
        const float* src = Wih + (size_t)row * E_ + k0;
        f32x4 z = {0.f, 0.f, 0.f, 0.f};
        f32x4 p0 = (k0 + 4 <= E_) ? *(const f32x4*)src : z;
        f32x4 p1 = (k0 + 8 <= E_) ? *(const f32x4*)(src + 4) : z;
        bf16x8 hi, lo; cvt8(p0, p1, hi, lo);
        int off = ((((row >> 4) * 4 + (gk >> 2)) * 4 + (gk & 3)) * 16 + (row & 15)) * 8;
        *(bf16x8*)&Bh[off] = hi; *(bf16x8*)&Bl[off] = lo;
    }
    __syncthreads();
    // stage A granules: gathered embedding rows, row length 100
    for (int g = tid; g < 2048; g += 512) {
        int row = g >> 4, gk = g & 15;
        int k0 = gk * 8;
        const float* src = emb + (size_t)xidx[row] * E_ + k0;
        f32x4 z = {0.f, 0.f, 0.f, 0.f};
        f32x4 p0 = (k0 + 4 <= E_) ? *(const f32x4*)src : z;
        f32x4 p1 = (k0 + 8 <= E_) ? *(const f32x4*)(src + 4) : z;
        bf16x8 hi, lo; cvt8(p0, p1, hi, lo);
        int off = ((((row >> 4) * 4 + (gk >> 2)) * 4 + (gk & 3)) * 16 + (row & 15)) * 8;
        *(bf16x8*)&Ah[off] = hi; *(bf16x8*)&Al[off] = lo;
    }
    __syncthreads();

    const int lane = tid & 63, w = tid >> 6;
    const int sub = lane >> 4, rc = lane & 15;
    const int mt0 = (w & 3) * 2, nt0 = (w >> 2) * 4;
    f32x4 acc[2][4];
#pragma unroll
    for (int m = 0; m < 2; ++m)
#pragma unroll
        for (int n = 0; n < 4; ++n) acc[m][n] = (f32x4){0.f, 0.f, 0.f, 0.f};

#pragma unroll
    for (int kc = 0; kc < 4; ++kc) {
        bf16x8 a_h[2], a_l[2];
#pragma unroll
        for (int m = 0; m < 2; ++m) {
            int off = ((((mt0 + m) * 4 + kc) * 4 + sub) * 16 + rc) * 8;
            a_h[m] = *(const bf16x8*)&Ah[off];
            a_l[m] = *(const bf16x8*)&Al[off];
        }
#pragma unroll
        for (int n = 0; n < 4; ++n) {
            int off = ((((nt0 + n) * 4 + kc) * 4 + sub) * 16 + rc) * 8;
            bf16x8 b_h = *(const bf16x8*)&Bh[off];
            bf16x8 b_l = *(const bf16x8*)&Bl[off];
#pragma unroll
            for (int m = 0; m < 2; ++m) {
                acc[m][n] = mfma16(a_h[m], b_h, acc[m][n]);
                acc[m][n] = mfma16(a_l[m], b_h, acc[m][n]);
                acc[m][n] = mfma16(a_h[m], b_l, acc[m][n]);
            }
        }
    }
#pragma unroll
    for (int n = 0; n < 4; ++n) {
        int ic = (nt0 + n) * 16 + rc;
        float bias = bih[ic] + bhh[ic];
#pragma unroll
        for (int m = 0; m < 2; ++m) {
            int rg = (mt0 + m) * 16 + sub * 4;
            float* dst = xp + ((size_t)tq * B_ + b0 + rg) * H_ + ic;
#pragma unroll
            for (int r = 0; r < 4; ++r) dst[(size_t)r * H_] = acc[m][n][r] + bias;
        }
    }
}

// ---------------------------------------------------------------------------
// K2: RNN scan. 64 blocks x 16 batch rows; 8 waves, wave w owns h-cols [16w,16w+16).
// W_hh^T fragments in registers; h ping-pongs via LDS granules; 1 barrier/step.
// ---------------------------------------------------------------------------
__global__ __launch_bounds__(512, 1) void k2_rnn(
    const float* __restrict__ xp, const float* __restrict__ Whh,
    float* __restrict__ hstate, int t0, int len)
{
    __shared__ __bf16 Ah[2][2048], Al[2][2048];
    const int tid = threadIdx.x;
    const int lane = tid & 63, w = tid >> 6;
    const int b0 = blockIdx.x * 16;
    const int sub = lane >> 4, rowq = lane & 15;
    const int i = (w << 4) | rowq;            // this lane's output h-column
    const int kcw = i >> 5, subw = (i >> 3) & 3, ew = i & 7;
    const int rowbase = sub * 4;

    // B-operand fragments: B[k][i] = W_hh[i][k]; kept in regs for whole kernel
    bf16x8 wbh[4], wbl[4];
#pragma unroll
    for (int kc = 0; kc < 4; ++kc) {
        const float* src = Whh + (size_t)i * H_ + kc * 32 + sub * 8;
        f32x4 p0 = *(const f32x4*)src;
        f32x4 p1 = *(const f32x4*)(src + 4);
        cvt8(p0, p1, wbh[kc], wbl[kc]);
    }

    // stage initial h into buffer 0
    if (t0 == 0) {
        for (int idx = tid; idx < 2048; idx += 512) {
            Ah[0][idx] = (__bf16)0.0f; Al[0][idx] = (__bf16)0.0f;
        }
    } else {
#pragma unroll
        for (int j = 0; j < 4; ++j) {
            int idx = tid * 4 + j;
            int row = idx >> 7, ii = idx & 127;
            float v = hstate[(size_t)(b0 + row) * H_ + ii];
            __bf16 hi, lo; split_bf16(v, hi, lo);
            int off = ((((ii >> 5) * 4) + ((ii >> 3) & 3)) * 16 + row) * 8 + (ii & 7);
            Ah[0][off] = hi; Al[0][off] = lo;
        }
    }
    __syncthreads();

    int p = 0;
    f32x4 xt;
    {
        const float* xpp = xp + ((size_t)b0 + rowbase) * H_ + i;
#pragma unroll
        for (int r = 0; r < 4; ++r) xt[r] = xpp[(size_t)r * H_];
    }

    for (int tq = 0; tq < len; ++tq) {
        f32x4 xtn;
        if (tq + 1 < len) {   // prefetch next step's xt (hides HBM/L3 latency)
            const float* xpp = xp + ((size_t)(tq + 1) * B_ + b0 + rowbase) * H_ + i;
#pragma unroll
            for (int r = 0; r < 4; ++r) xtn[r] = xpp[(size_t)r * H_];
        }
        bf16x8 ah[4], al[4];
#pragma unroll
        for (int kc = 0; kc < 4; ++kc) {
            int off = ((kc * 4 + sub) * 16 + rowq) * 8;
            ah[kc] = *(const bf16x8*)&Ah[p][off];
            al[kc] = *(const bf16x8*)&Al[p][off];
        }
        f32x4 acc0 = xt;                       // C reg r <-> row rowbase+r
        f32x4 acc1 = {0.f, 0.f, 0.f, 0.f};
#pragma unroll
        for (int kc = 0; kc < 4; ++kc) {
            if (kc & 1) {
                acc1 = mfma16(ah[kc], wbh[kc], acc1);
                acc1 = mfma16(al[kc], wbh[kc], acc1);
                acc1 = mfma16(ah[kc], wbl[kc], acc1);
            } else {
                acc0 = mfma16(ah[kc], wbh[kc], acc0);
                acc0 = mfma16(al[kc], wbh[kc], acc0);
                acc0 = mfma16(ah[kc], wbl[kc], acc0);
            }
        }
        f32x4 s = acc0 + acc1;
        int wb = ((kcw * 4 + subw) * 16 + rowbase) * 8 + ew;
#pragma unroll
        for (int r = 0; r < 4; ++r) {
            float h = tanhf(s[r]);
            __bf16 hi, lo; split_bf16(h, hi, lo);
            Ah[p ^ 1][wb + r * 8] = hi;
            Al[p ^ 1][wb + r * 8] = lo;
            if (tq == len - 1)
                hstate[(size_t)(b0 + rowbase + r) * H_ + i] = h;
        }
        __syncthreads();
        p ^= 1;
        xt = xtn;
    }
}

// ---------------------------------------------------------------------------
// K3: out[b][v] = h[b] @ W_fc[v]^T + b_fc[v]. Tile 128(b) x 128(v), K=128.
// grid: (V/128, B/128) ; block 512.
// ---------------------------------------------------------------------------
__global__ __launch_bounds__(512, 1) void k3_head(
    const float* __restrict__ hstate, const float* __restrict__ Wfc,
    const float* __restrict__ bfc, float* __restrict__ out)
{
    __shared__ __bf16 Ah[16384], Al[16384], Bh[16384], Bl[16384];
    const int tid = threadIdx.x;
    const int v0 = blockIdx.x * 128;
    const int b0 = blockIdx.y * 128;

    // stage A: h rows (K=128 exact)
    for (int g = tid; g < 2048; g += 512) {
        int row = g >> 4, gk = g & 15;
        int k0 = gk * 8;
        const float* src = hstate + (size_t)(b0 + row) * H_ + k0;
        f32x4 p0 = *(const f32x4*)src;
        f32x4 p1 = *(const f32x4*)(src + 4);
        bf16x8 hi, lo; cvt8(p0, p1, hi, lo);
        int off = ((((row >> 4) * 4 + (gk >> 2)) * 4 + (gk & 3)) * 16 + (row & 15)) * 8;
        *(bf16x8*)&Ah[off] = hi; *(bf16x8*)&Al[off] = lo;
    }
    // stage B: B[k][v] = W_fc[v][k]
    for (int g = tid; g < 2048; g += 512) {
        int row = g >> 4, gk = g & 15;
        int k0 = gk * 8;
        const float* src = Wfc + (size_t)(v0 + row) * H_ + k0;
        f32x4 p0 = *(const f32x4*)src;
        f32x4 p1 = *(const f32x4*)(src + 4);
        bf16x8 hi, lo; cvt8(p0, p1, hi, lo);
        int off = ((((row >> 4) * 4 + (gk >> 2)) * 4 + (gk & 3)) * 16 + (row & 15)) * 8;
        *(bf16x8*)&Bh[off] = hi; *(bf16x8*)&Bl[off] = lo;
    }
    __syncthreads();

    const int lane = tid & 63, w = tid >> 6;
    const int sub = lane >> 4, rc = lane & 15;
    const int mt0 = (w & 3) * 2, nt0 = (w >> 2) * 4;
    f32x4 acc[2][4];
#pragma unroll
    for (int m = 0; m < 2; ++m)
#pragma unroll
        for (int n = 0; n < 4; ++n) acc[m][n] = (f32x4){0.f, 0.f, 0.f, 0.f};

#pragma unroll
    for (int kc = 0; kc < 4; ++kc) {
        bf16x8 a_h[2], a_l[2];
#pragma unroll
        for (int m = 0; m < 2; ++m) {
            int off = ((((mt0 + m) * 4 + kc) * 4 + sub) * 16 + rc) * 8;
            a_h[m] = *(const bf16x8*)&Ah[off];
            a_l[m] = *(const bf16x8*)&Al[off];
        }
#pragma unroll
        for (int n = 0; n < 4; ++n) {
            int off = ((((nt0 + n) * 4 + kc) * 4 + sub) * 16 + rc) * 8;
            bf16x8 b_h = *(const bf16x8*)&Bh[off];
            bf16x8 b_l = *(const bf16x8*)&Bl[off];
#pragma unroll
            for (int m = 0; m < 2; ++m) {
                acc[m][n] = mfma16(a_h[m], b_h, acc[m][n]);
                acc[m][n] = mfma16(a_l[m], b_h, acc[m][n]);
                acc[m][n] = mfma16(a_h[m], b_l, acc[m][n]);
            }
        }
    }
#pragma unroll
    for (int n = 0; n < 4; ++n) {
        int ic = (nt0 + n) * 16 + rc;
        float bias = bfc[v0 + ic];
#pragma unroll
        for (int m = 0; m < 2; ++m) {
            int rg = (mt0 + m) * 16 + sub * 4;
            float* dst = out + (size_t)(b0 + rg) * V_ + v0 + ic;
#pragma unroll
            for (int r = 0; r < 4; ++r) dst[(size_t)r * V_] = acc[m][n][r] + bias;
        }
    }
}

extern "C" void kernel_launch(void* const* d_in, const int* in_sizes, int n_in,
                              void* d_out, int out_size, void* d_ws, size_t ws_size,
                              hipStream_t stream) {
    const int*   x   = (const int*)d_in[0];
    const float* emb = (const float*)d_in[1];
    const float* Wih = (const float*)d_in[2];
    const float* Whh = (const float*)d_in[3];
    const float* bih = (const float*)d_in[4];
    const float* bhh = (const float*)d_in[5];
    const float* Wfc = (const float*)d_in[6];
    const float* bfc = (const float*)d_in[7];
    float* out = (float*)d_out;

    const size_t per_t  = (size_t)B_ * H_ * sizeof(float);  // 512 KB / timestep
    const size_t hbytes = (size_t)B_ * H_ * sizeof(float);

    float* hstate = (float*)d_ws;
    float* xp;
    int Tc;
    if (ws_size >= hbytes + per_t) {
        xp = hstate + (size_t)B_ * H_;
        size_t tcap = (ws_size - hbytes) / per_t;
        Tc = tcap >= (size_t)T_ ? T_ : (int)tcap;
    } else {
        // fallback: stage xp chunks in d_out (250 timesteps fit); K3 overwrites last
        xp = out;
        Tc = 250;
    }

    for (int t0 = 0; t0 < T_; t0 += Tc) {
        int len = (T_ - t0) < Tc ? (T_ - t0) : Tc;
        k1_xproj<<<dim3(8, len), 512, 0, stream>>>(x, emb, Wih, bih, bhh, xp, t0);
        k2_rnn<<<dim3(64), 512, 0, stream>>>(xp, Whh, hstate, t0, len);
    }
    k3_head<<<dim3(250, 8), 512, 0, stream>>>(hstate, Wfc, bfc, out);
}

// Round 2
// 274.730 us; speedup vs baseline: 1.2493x; 1.2493x over previous
//
#include <hip/hip_runtime.h>
#include <hip/hip_bf16.h>

#define V_ 32000
#define E_ 100
#define H_ 128
#define B_ 1024
#define T_ 256

typedef float f32x4 __attribute__((ext_vector_type(4)));
typedef __bf16 bf16x8 __attribute__((ext_vector_type(8)));
typedef __bf16 bf16x4 __attribute__((ext_vector_type(4)));

__device__ __forceinline__ f32x4 mfma16(bf16x8 a, bf16x8 b, f32x4 c) {
    return __builtin_amdgcn_mfma_f32_16x16x32_bf16(a, b, c, 0, 0, 0);
}

__device__ __forceinline__ void split_bf16(float v, __bf16& hi, __bf16& lo) {
    hi = (__bf16)v;
    lo = (__bf16)(v - (float)hi);
}

__device__ __forceinline__ void cvt8(f32x4 p0, f32x4 p1, bf16x8& hi, bf16x8& lo) {
#pragma unroll
    for (int e = 0; e < 4; ++e) {
        __bf16 h1, l1; split_bf16(p0[e], h1, l1);
        hi[e] = h1; lo[e] = l1;
        __bf16 h2, l2; split_bf16(p1[e], h2, l2);
        hi[4 + e] = h2; lo[4 + e] = l2;
    }
}

// ---------------------------------------------------------------------------
// K1: xp[tq][b][h] = emb[x[b,t]] @ W_ih^T + b_ih + b_hh   (K=100 padded to 128)
// grid: (B/128, len) ; block 512 (8 waves). Tile 128(batch) x 128(H).
// ---------------------------------------------------------------------------
__global__ __launch_bounds__(512, 1) void k1_xproj(
    const int* __restrict__ x, const float* __restrict__ emb,
    const float* __restrict__ Wih, const float* __restrict__ bih,
    const float* __restrict__ bhh, float* __restrict__ xp, int t0)
{
    __shared__ __bf16 Ah[16384], Al[16384], Bh[16384], Bl[16384];
    __shared__ int xidx[128];
    const int tid = threadIdx.x;
    const int b0 = blockIdx.x * 128;
    const int tq = blockIdx.y;
    const int t = t0 + tq;

    if (tid < 128) xidx[tid] = x[(size_t)(b0 + tid) * T_ + t];

    // stage B granules: B[k][h] = W_ih[h][k], rows = h, row length 100
    for (int g = tid; g < 2048; g += 512) {
        int row = g >> 4, gk = g & 15;
        int k0 = gk * 8;
        const float* src = Wih + (size_t)row * E_ + k0;
        f32x4 z = {0.f, 0.f, 0.f, 0.f};
        f32x4 p0 = (k0 + 4 <= E_) ? *(const f32x4*)src : z;
        f32x4 p1 = (k0 + 8 <= E_) ? *(const f32x4*)(src + 4) : z;
        bf16x8 hi, lo; cvt8(p0, p1, hi, lo);
        int off = ((((row >> 4) * 4 + (gk >> 2)) * 4 + (gk & 3)) * 16 + (row & 15)) * 8;
        *(bf16x8*)&Bh[off] = hi; *(bf16x8*)&Bl[off] = lo;
    }
    __syncthreads();
    // stage A granules: gathered embedding rows, row length 100
    for (int g = tid; g < 2048; g += 512) {
        int row = g >> 4, gk = g & 15;
        int k0 = gk * 8;
        const float* src = emb + (size_t)xidx[row] * E_ + k0;
        f32x4 z = {0.f, 0.f, 0.f, 0.f};
        f32x4 p0 = (k0 + 4 <= E_) ? *(const f32x4*)src : z;
        f32x4 p1 = (k0 + 8 <= E_) ? *(const f32x4*)(src + 4) : z;
        bf16x8 hi, lo; cvt8(p0, p1, hi, lo);
        int off = ((((row >> 4) * 4 + (gk >> 2)) * 4 + (gk & 3)) * 16 + (row & 15)) * 8;
        *(bf16x8*)&Ah[off] = hi; *(bf16x8*)&Al[off] = lo;
    }
    __syncthreads();

    const int lane = tid & 63, w = tid >> 6;
    const int sub = lane >> 4, rc = lane & 15;
    const int mt0 = (w & 3) * 2, nt0 = (w >> 2) * 4;
    f32x4 acc[2][4];
#pragma unroll
    for (int m = 0; m < 2; ++m)
#pragma unroll
        for (int n = 0; n < 4; ++n) acc[m][n] = (f32x4){0.f, 0.f, 0.f, 0.f};

#pragma unroll
    for (int kc = 0; kc < 4; ++kc) {
        bf16x8 a_h[2], a_l[2];
#pragma unroll
        for (int m = 0; m < 2; ++m) {
            int off = ((((mt0 + m) * 4 + kc) * 4 + sub) * 16 + rc) * 8;
            a_h[m] = *(const bf16x8*)&Ah[off];
            a_l[m] = *(const bf16x8*)&Al[off];
        }
#pragma unroll
        for (int n = 0; n < 4; ++n) {
            int off = ((((nt0 + n) * 4 + kc) * 4 + sub) * 16 + rc) * 8;
            bf16x8 b_h = *(const bf16x8*)&Bh[off];
            bf16x8 b_l = *(const bf16x8*)&Bl[off];
#pragma unroll
            for (int m = 0; m < 2; ++m) {
                acc[m][n] = mfma16(a_h[m], b_h, acc[m][n]);
                acc[m][n] = mfma16(a_l[m], b_h, acc[m][n]);
                acc[m][n] = mfma16(a_h[m], b_l, acc[m][n]);
            }
        }
    }
#pragma unroll
    for (int n = 0; n < 4; ++n) {
        int ic = (nt0 + n) * 16 + rc;
        float bias = bih[ic] + bhh[ic];
#pragma unroll
        for (int m = 0; m < 2; ++m) {
            int rg = (mt0 + m) * 16 + sub * 4;
            float* dst = xp + ((size_t)tq * B_ + b0 + rg) * H_ + ic;
#pragma unroll
            for (int r = 0; r < 4; ++r) dst[(size_t)r * H_] = acc[m][n][r] + bias;
        }
    }
}

// ---------------------------------------------------------------------------
// K2: RNN scan, operand-swapped: Z = W_hh · h^T so the MFMA output layout
// (col = batch) matches next step's B-operand layout (col = batch).
// 64 blocks x 16 batch rows; 8 waves; wave w owns hidden-out rows [16w,16w+16).
// W_hh A-fragments (hi/lo) live in registers; h exchanged via row-major
// bf16 LDS h[16][136] (pad 17x16B -> conflict-free b64 writes & b128 reads).
// Raw s_barrier + lgkmcnt-only wait keeps the xt prefetch in flight.
// ---------------------------------------------------------------------------
__global__ __launch_bounds__(512, 1) void k2_rnn(
    const float* __restrict__ xp, const float* __restrict__ Whh,
    float* __restrict__ hstate, int t0, int len)
{
    const int LDH = 136;
    __shared__ __align__(16) __bf16 Hhi[2][16 * 136];
    __shared__ __align__(16) __bf16 Hlo[2][16 * 136];
    const int tid = threadIdx.x;
    const int lane = tid & 63, w = tid >> 6;
    const int b0 = blockIdx.x * 16;
    const int sub = lane >> 4, c = lane & 15;

    // A-operand fragments: W_hh rows [16w,16w+16), split hi/lo; loop-invariant
    bf16x8 wah[4], wal[4];
#pragma unroll
    for (int kc = 0; kc < 4; ++kc) {
        const float* src = Whh + (size_t)(w * 16 + c) * H_ + kc * 32 + sub * 8;
        f32x4 p0 = *(const f32x4*)src;
        f32x4 p1 = *(const f32x4*)(src + 4);
        cvt8(p0, p1, wah[kc], wal[kc]);
    }

    if (t0 == 0) {
        for (int idx = tid; idx < 16 * 136; idx += 512) {
            Hhi[0][idx] = (__bf16)0.0f;
            Hlo[0][idx] = (__bf16)0.0f;
        }
    } else {
        const int c2 = tid >> 5, k0 = (tid & 31) * 4;
        f32x4 v = *(const f32x4*)&hstate[(size_t)(b0 + c2) * H_ + k0];
        bf16x4 hi4, lo4;
#pragma unroll
        for (int r = 0; r < 4; ++r) {
            __bf16 hb = (__bf16)v[r];
            hi4[r] = hb;
            lo4[r] = (__bf16)(v[r] - (float)hb);
        }
        *(bf16x4*)&Hhi[0][c2 * LDH + k0] = hi4;
        *(bf16x4*)&Hlo[0][c2 * LDH + k0] = lo4;
    }
    __syncthreads();

    const int hcol = w * 16 + sub * 4;   // this lane's 4 hidden-out rows base
    int p = 0;
    f32x4 xt = *(const f32x4*)(xp + ((size_t)b0 + c) * H_ + hcol);

    for (int tq = 0; tq < len; ++tq) {
        // prefetch next xt (coalesced f32x4); stays in flight across barrier
        int tn = (tq + 1 < len) ? tq + 1 : tq;
        f32x4 xtn = *(const f32x4*)(xp + ((size_t)tn * B_ + b0 + c) * H_ + hcol);

        bf16x8 bh[4], bl[4];
#pragma unroll
        for (int kc = 0; kc < 4; ++kc) {
            bh[kc] = *(const bf16x8*)&Hhi[p][c * LDH + kc * 32 + sub * 8];
            bl[kc] = *(const bf16x8*)&Hlo[p][c * LDH + kc * 32 + sub * 8];
        }
        f32x4 a0 = xt;
        f32x4 a1 = {0.f, 0.f, 0.f, 0.f};
        f32x4 a2 = {0.f, 0.f, 0.f, 0.f};
        f32x4 a3 = {0.f, 0.f, 0.f, 0.f};
        // 4 independent chains of depth 3
        a0 = mfma16(wah[0], bh[0], a0);
        a1 = mfma16(wah[1], bh[1], a1);
        a2 = mfma16(wah[2], bh[2], a2);
        a3 = mfma16(wah[3], bh[3], a3);
        a0 = mfma16(wal[0], bh[0], a0);
        a1 = mfma16(wal[1], bh[1], a1);
        a2 = mfma16(wal[2], bh[2], a2);
        a3 = mfma16(wal[3], bh[3], a3);
        a0 = mfma16(wah[0], bl[0], a0);
        a1 = mfma16(wah[1], bl[1], a1);
        a2 = mfma16(wah[2], bl[2], a2);
        a3 = mfma16(wah[3], bl[3], a3);
        f32x4 s = (a0 + a1) + (a2 + a3);

        // fast tanh: 1 - 2/(exp2(2x*log2e)+1); exact at +/-inf, ~1ulp mid
        f32x4 hv;
        bf16x4 hi4, lo4;
#pragma unroll
        for (int r = 0; r < 4; ++r) {
            float x2 = s[r] * 2.8853900817779268f;
            float e;
            asm("v_exp_f32 %0, %1" : "=v"(e) : "v"(x2));
            float ep1 = e + 1.0f;
            float rcp;
            asm("v_rcp_f32 %0, %1" : "=v"(rcp) : "v"(ep1));
            float h = 1.0f - 2.0f * rcp;
            hv[r] = h;
            __bf16 hb = (__bf16)h;
            hi4[r] = hb;
            lo4[r] = (__bf16)(h - (float)hb);
        }
        if (tq == len - 1)
            *(f32x4*)&hstate[(size_t)(b0 + c) * H_ + hcol] = hv;

        const int wb = c * LDH + hcol;
        *(bf16x4*)&Hhi[p ^ 1][wb] = hi4;
        *(bf16x4*)&Hlo[p ^ 1][wb] = lo4;

        asm volatile("s_waitcnt lgkmcnt(0)" ::: "memory");
        __builtin_amdgcn_s_barrier();
        __builtin_amdgcn_sched_barrier(0);
        p ^= 1;
        xt = xtn;
    }
}

// ---------------------------------------------------------------------------
// K3: out[b][v] = h[b] @ W_fc[v]^T + b_fc[v]. Tile 128(b) x 128(v), K=128.
// grid: (V/128, B/128) ; block 512.
// ---------------------------------------------------------------------------
__global__ __launch_bounds__(512, 1) void k3_head(
    const float* __restrict__ hstate, const float* __restrict__ Wfc,
    const float* __restrict__ bfc, float* __restrict__ out)
{
    __shared__ __bf16 Ah[16384], Al[16384], Bh[16384], Bl[16384];
    const int tid = threadIdx.x;
    const int v0 = blockIdx.x * 128;
    const int b0 = blockIdx.y * 128;

    // stage A: h rows (K=128 exact)
    for (int g = tid; g < 2048; g += 512) {
        int row = g >> 4, gk = g & 15;
        int k0 = gk * 8;
        const float* src = hstate + (size_t)(b0 + row) * H_ + k0;
        f32x4 p0 = *(const f32x4*)src;
        f32x4 p1 = *(const f32x4*)(src + 4);
        bf16x8 hi, lo; cvt8(p0, p1, hi, lo);
        int off = ((((row >> 4) * 4 + (gk >> 2)) * 4 + (gk & 3)) * 16 + (row & 15)) * 8;
        *(bf16x8*)&Ah[off] = hi; *(bf16x8*)&Al[off] = lo;
    }
    // stage B: B[k][v] = W_fc[v][k]
    for (int g = tid; g < 2048; g += 512) {
        int row = g >> 4, gk = g & 15;
        int k0 = gk * 8;
        const float* src = Wfc + (size_t)(v0 + row) * H_ + k0;
        f32x4 p0 = *(const f32x4*)src;
        f32x4 p1 = *(const f32x4*)(src + 4);
        bf16x8 hi, lo; cvt8(p0, p1, hi, lo);
        int off = ((((row >> 4) * 4 + (gk >> 2)) * 4 + (gk & 3)) * 16 + (row & 15)) * 8;
        *(bf16x8*)&Bh[off] = hi; *(bf16x8*)&Bl[off] = lo;
    }
    __syncthreads();

    const int lane = tid & 63, w = tid >> 6;
    const int sub = lane >> 4, rc = lane & 15;
    const int mt0 = (w & 3) * 2, nt0 = (w >> 2) * 4;
    f32x4 acc[2][4];
#pragma unroll
    for (int m = 0; m < 2; ++m)
#pragma unroll
        for (int n = 0; n < 4; ++n) acc[m][n] = (f32x4){0.f, 0.f, 0.f, 0.f};

#pragma unroll
    for (int kc = 0; kc < 4; ++kc) {
        bf16x8 a_h[2], a_l[2];
#pragma unroll
        for (int m = 0; m < 2; ++m) {
            int off = ((((mt0 + m) * 4 + kc) * 4 + sub) * 16 + rc) * 8;
            a_h[m] = *(const bf16x8*)&Ah[off];
            a_l[m] = *(const bf16x8*)&Al[off];
        }
#pragma unroll
        for (int n = 0; n < 4; ++n) {
            int off = ((((nt0 + n) * 4 + kc) * 4 + sub) * 16 + rc) * 8;
            bf16x8 b_h = *(const bf16x8*)&Bh[off];
            bf16x8 b_l = *(const bf16x8*)&Bl[off];
#pragma unroll
            for (int m = 0; m < 2; ++m) {
                acc[m][n] = mfma16(a_h[m], b_h, acc[m][n]);
                acc[m][n] = mfma16(a_l[m], b_h, acc[m][n]);
                acc[m][n] = mfma16(a_h[m], b_l, acc[m][n]);
            }
        }
    }
#pragma unroll
    for (int n = 0; n < 4; ++n) {
        int ic = (nt0 + n) * 16 + rc;
        float bias = bfc[v0 + ic];
#pragma unroll
        for (int m = 0; m < 2; ++m) {
            int rg = (mt0 + m) * 16 + sub * 4;
            float* dst = out + (size_t)(b0 + rg) * V_ + v0 + ic;
#pragma unroll
            for (int r = 0; r < 4; ++r) dst[(size_t)r * V_] = acc[m][n][r] + bias;
        }
    }
}

extern "C" void kernel_launch(void* const* d_in, const int* in_sizes, int n_in,
                              void* d_out, int out_size, void* d_ws, size_t ws_size,
                              hipStream_t stream) {
    const int*   x   = (const int*)d_in[0];
    const float* emb = (const float*)d_in[1];
    const float* Wih = (const float*)d_in[2];
    const float* Whh = (const float*)d_in[3];
    const float* bih = (const float*)d_in[4];
    const float* bhh = (const float*)d_in[5];
    const float* Wfc = (const float*)d_in[6];
    const float* bfc = (const float*)d_in[7];
    float* out = (float*)d_out;

    const size_t per_t  = (size_t)B_ * H_ * sizeof(float);  // 512 KB / timestep
    const size_t hbytes = (size_t)B_ * H_ * sizeof(float);

    float* hstate = (float*)d_ws;
    float* xp;
    int Tc;
    if (ws_size >= hbytes + per_t) {
        xp = hstate + (size_t)B_ * H_;
        size_t tcap = (ws_size - hbytes) / per_t;
        Tc = tcap >= (size_t)T_ ? T_ : (int)tcap;
    } else {
        // fallback: stage xp chunks in d_out (250 timesteps fit); K3 overwrites last
        xp = out;
        Tc = 250;
    }

    for (int t0 = 0; t0 < T_; t0 += Tc) {
        int len = (T_ - t0) < Tc ? (T_ - t0) : Tc;
        k1_xproj<<<dim3(8, len), 512, 0, stream>>>(x, emb, Wih, bih, bhh, xp, t0);
        k2_rnn<<<dim3(64), 512, 0, stream>>>(xp, Whh, hstate, t0, len);
    }
    k3_head<<<dim3(250, 8), 512, 0, stream>>>(hstate, Wfc, bfc, out);
}